// Round 9
// baseline (125.502 us; speedup 1.0000x reference)
//
#include <hip/hip_runtime.h>
#include <math.h>

#define WIN 11
#define OH 32               // output rows per tile
#define OW 64               // output cols per tile
#define RROWS 42            // raw rows staged (OH + 10)
#define RCH 19              // 16B chunks per raw row (76 floats)
#define RSTRF 76            // raw row stride in floats
#define VSTRH 80            // vb row stride in halfs (160 B)
#define PLANEH (OH * VSTRH) // 2560 halfs per channel
#define IMG 512
#define OUTD 502            // 512 - 10 (VALID)
#define NIMG 64

typedef _Float16 h2 __attribute__((ext_vector_type(2)));
typedef _Float16 h8 __attribute__((ext_vector_type(8)));
typedef __fp16   fp16x2 __attribute__((ext_vector_type(2)));

typedef __attribute__((address_space(3))) unsigned       lds_u32;
typedef const __attribute__((address_space(1))) unsigned glb_u32;

struct GW { unsigned whp[WIN]; };   // fp16 weight splatted into both halves

union U32H2 { unsigned u; h2 h; fp16x2 f; };
__device__ inline h2 wsplat(unsigned u) { U32H2 x; x.u = u; return x.h; }
__device__ inline h2 alignh(h2 hi, h2 lo) {   // {lo[1], hi[0]}
    U32H2 a, b, r; a.h = lo; b.h = hi;
    r.u = (a.u >> 16) | (b.u << 16);
    return r.h;
}
__device__ inline h2 pkrtz(float a, float b) {
    U32H2 x; x.f = __builtin_amdgcn_cvt_pkrtz(a, b); return x.h;
}
__device__ inline void gl_lds16(const void* g, void* l) {
    __builtin_amdgcn_global_load_lds((glb_u32*)g, (lds_u32*)l, 16, 0, 0);
}

__global__ __launch_bounds__(64) void ssim_zero(double* acc) {
    if (threadIdx.x == 0) acc[0] = 0.0;
}

__global__ __launch_bounds__(256, 3) void ssim_kernel(
    const float* __restrict__ X, const float* __restrict__ Y,
    double* __restrict__ acc, GW gw)
{
    __shared__ float raw[2 * RROWS * RSTRF];   // 25536 B (X then Y plane)
    __shared__ _Float16 vb[5 * PLANEH];        // 25600 B
    __shared__ float red[4];

    const int tid = threadIdx.x;
    const int tC = blockIdx.x, tR = blockIdx.y, b = blockIdx.z;
    const int gr0 = tR * OH, gc0 = tC * OW;
    const float* __restrict__ Xb = X + (size_t)b * (IMG * IMG);
    const float* __restrict__ Yb = Y + (size_t)b * (IMG * IMG);

    // ---- Phase A: async DMA raw tiles into LDS (global_load_lds, 16B).
    // Chunk c: img = c/798, row = rem/19, chunk col = rem%19. LDS is linear:
    // HW writes at (wave-uniform base) + lane*16; with c = tid + 256*iter the
    // lane offset equals c - (c & ~63), so base = raw + (c & ~63)*16.
    {
        const int totalc = 2 * RROWS * RCH;   // 1596
        for (int c = tid; c < totalc; c += 256) {
            int img = (c >= RROWS * RCH) ? 1 : 0;
            int rem = c - img * (RROWS * RCH);
            int row = rem / RCH;
            int chk = rem - row * RCH;
            int grow = gr0 + row; if (grow > IMG - 1) grow = IMG - 1;
            int gcol = gc0 + chk * 4; if (gcol > IMG - 4) gcol = IMG - 4;
            const float* src = (img ? Yb : Xb) + (size_t)grow * IMG + gcol;
            gl_lds16(src, (char*)raw + (size_t)(c & ~63) * 16);
        }
    }
    __syncthreads();   // compiler drains vmcnt(0) before s_barrier

    // ---- Phase B: vertical 11-tap conv of 5 derived channels from LDS,
    // packed-fp16. 296 tasks of 4 rows x 2 cols; threads 0..39 take two.
    for (int t = tid; t < 296; t += 256) {
        const int rg = t / 37, cp = t - rg * 37;
        const int r0 = rg * 4;
        h2 a[5][4] = {};
        #pragma unroll
        for (int k = 0; k < 4 + WIN - 1; ++k) {
            const float2 xv = *reinterpret_cast<const float2*>(&raw[(r0 + k) * RSTRF + cp * 2]);
            const float2 yv = *reinterpret_cast<const float2*>(&raw[RROWS * RSTRF + (r0 + k) * RSTRF + cp * 2]);
            h2 x = pkrtz(xv.x, xv.y);
            h2 y = pkrtz(yv.x, yv.y);
            h2 xx = x * x, yy = y * y, xy = x * y;
            #pragma unroll
            for (int i2 = 0; i2 < 4; ++i2) {
                const int tt = k - i2;
                if (tt >= 0 && tt < WIN) {        // compile-time after unroll
                    const h2 wt = wsplat(gw.whp[tt]);
                    a[0][i2] += wt * x;
                    a[1][i2] += wt * y;
                    a[2][i2] += wt * xx;
                    a[3][i2] += wt * yy;
                    a[4][i2] += wt * xy;
                }
            }
        }
        #pragma unroll
        for (int ch = 0; ch < 5; ++ch) {
            #pragma unroll
            for (int i2 = 0; i2 < 4; ++i2) {
                *reinterpret_cast<h2*>(&vb[ch * PLANEH + (r0 + i2) * VSTRH + cp * 2]) = a[ch][i2];
            }
        }
    }
    __syncthreads();

    // ---- Phase C: horizontal 11-tap conv (packed fp16) + SSIM (f32).
    const int r   = tid >> 3;         // 0..31
    const int c0h = (tid & 7) * 8;    // 0..56
    const _Float16* rb = &vb[r * VSTRH];

    h2 m[5][4];
    #pragma unroll
    for (int ch = 0; ch < 5; ++ch) {
        const _Float16* p = rb + ch * PLANEH;
        h8 v0 = *reinterpret_cast<const h8*>(p + c0h);
        h8 v1 = *reinterpret_cast<const h8*>(p + c0h + 8);
        h2 e8 = *reinterpret_cast<const h2*>(p + c0h + 16);
        h2 e[9];
        #pragma unroll
        for (int j = 0; j < 4; ++j) e[j]     = h2{ v0[2*j], v0[2*j+1] };
        #pragma unroll
        for (int j = 0; j < 4; ++j) e[4 + j] = h2{ v1[2*j], v1[2*j+1] };
        e[8] = e8;
        h2 o[8];
        #pragma unroll
        for (int j = 0; j < 8; ++j) o[j] = alignh(e[j+1], e[j]);

        #pragma unroll
        for (int pr = 0; pr < 4; ++pr) {
            h2 s = h2{ (_Float16)0, (_Float16)0 };
            #pragma unroll
            for (int u = 0; u < 6; ++u)           // even taps 0,2,4,6,8,10
                s += wsplat(gw.whp[2*u]) * e[pr + u];
            #pragma unroll
            for (int u = 0; u < 5; ++u)           // odd taps 1,3,5,7,9
                s += wsplat(gw.whp[2*u+1]) * o[pr + u];
            m[ch][pr] = s;
        }
    }

    const float C1 = 1e-4f, C2 = 9e-4f;
    float ssv[8];
    #pragma unroll
    for (int pr = 0; pr < 4; ++pr) {
        #pragma unroll
        for (int h = 0; h < 2; ++h) {
            float mu1 = (float)m[0][pr][h];
            float mu2 = (float)m[1][pr][h];
            float mu1s = mu1 * mu1, mu2s = mu2 * mu2, m12 = mu1 * mu2;
            float s1  = (float)m[2][pr][h] - mu1s;
            float s2  = (float)m[3][pr][h] - mu2s;
            float s12 = (float)m[4][pr][h] - m12;
            float num = (2.f * s12 + C2) * (2.f * m12 + C1);
            float den = (s1 + s2 + C2) * (mu1s + mu2s + C1);
            ssv[2*pr + h] = num * __builtin_amdgcn_rcpf(den);
        }
    }

    float lsum = 0.f;
    if (tR < 15 && tC < 7) {               // interior tile: no masking needed
        #pragma unroll
        for (int o = 0; o < 8; ++o) lsum += ssv[o];
    } else {
        const int ogr = gr0 + r;
        #pragma unroll
        for (int o = 0; o < 8; ++o) {
            const int ogc = gc0 + c0h + o;
            if (ogr < OUTD && ogc < OUTD) lsum += ssv[o];
        }
    }

    // ---- block reduce -> one double atomic per block ----
    #pragma unroll
    for (int off = 32; off > 0; off >>= 1)
        lsum += __shfl_down(lsum, off, 64);
    if ((tid & 63) == 0) red[tid >> 6] = lsum;
    __syncthreads();
    if (tid == 0) {
        float bs = red[0] + red[1] + red[2] + red[3];
        atomicAdd(acc, (double)bs);
    }
}

__global__ void ssim_finalize(const double* __restrict__ acc,
                              float* __restrict__ out) {
    out[0] = 1.0f - (float)(acc[0] / (double)((long long)NIMG * OUTD * OUTD));
}

static unsigned short f2h_rne(float f) {
    union { float f; unsigned u; } v; v.f = f;
    unsigned u = v.u;
    unsigned s = (u >> 16) & 0x8000u;
    int e = (int)((u >> 23) & 0xff) - 112;      // biased-15 exponent
    unsigned mant = u & 0x7fffffu;
    unsigned h = s | ((unsigned)e << 10) | (mant >> 13);
    unsigned rem = mant & 0x1fffu;
    if (rem > 0x1000u || (rem == 0x1000u && (h & 1u))) h++;
    return (unsigned short)h;
}

extern "C" void kernel_launch(void* const* d_in, const int* in_sizes, int n_in,
                              void* d_out, int out_size, void* d_ws, size_t ws_size,
                              hipStream_t stream) {
    const float* X = (const float*)d_in[0];
    const float* Y = (const float*)d_in[1];
    double* acc = (double*)d_ws;
    float* out = (float*)d_out;

    // Exact pytorch_msssim Gaussian window (double on host), rounded to fp16.
    GW gw;
    double c[WIN], s = 0.0;
    for (int i = 0; i < WIN; ++i) {
        double d = (double)i - (double)(WIN / 2);
        c[i] = exp(-(d * d) / (2.0 * 1.5 * 1.5));
        s += c[i];
    }
    for (int i = 0; i < WIN; ++i) {
        unsigned short hb = f2h_rne((float)(c[i] / s));
        gw.whp[i] = (unsigned)hb | ((unsigned)hb << 16);
    }

    ssim_zero<<<1, 64, 0, stream>>>(acc);
    dim3 grid(IMG / OW, IMG / OH, NIMG);   // (8, 16, 64)
    ssim_kernel<<<grid, 256, 0, stream>>>(X, Y, acc, gw);
    ssim_finalize<<<1, 1, 0, stream>>>(acc, out);
}